// Round 7
// baseline (126.351 us; speedup 1.0000x reference)
//
#include <hip/hip_runtime.h>

#define EPS 1e-6f

typedef __attribute__((ext_vector_type(8))) short short8;   // 8 x bf16 bits
typedef __attribute__((ext_vector_type(16))) float f32x16;  // MFMA 32x32 acc

__device__ __forceinline__ float elu1(float x) {
    // elu(x) + 1  ==  x > 0 ? x + 1 : exp(x)
    return x > 0.f ? x + 1.f : __expf(x);
}

// fp32 -> bf16 bits, round-to-nearest-even
__device__ __forceinline__ short f2bf(float x) {
    unsigned u = __float_as_uint(x);
    return (short)((u + 0x7FFFu + ((u >> 16) & 1u)) >> 16);
}

// ---------------------------------------------------------------------------
// Phase 1: KV partials via MFMA. One WAVE per (nh, chunk); wave-private LDS,
// no barriers, acc in AGPRs. Round-7 change: R6 was stuck at the scalar-load
// delivery ceiling (134MB/60us = 2.2 TB/s, 34 dword loads/step). Now: 9 wide
// VMEM instr/step (4 K-b128 + 4 V-b128 + 1 mask-b128) staged into LDS
// [2][16][68] fp32 (pad 68 -> conflict-free fragment reads), 2-deep register
// prefetch. Fragment mapping unchanged from R5/R6 (verified):
//   A (K'^T): lane holds d=l&31 (+32*td), k-elems s=8*(l>>5)+j
//   B (V):    lane holds m=l&31 (+32*tm), same k
//   C/D:      col=l&31, row=(r&3)+8*(r>>2)+4*(l>>5)
// ---------------------------------------------------------------------------
__global__ __launch_bounds__(64, 2) void kv_partial_kernel(
    const float* __restrict__ keys, const float* __restrict__ values,
    const float* __restrict__ mask, float* __restrict__ pkv,
    float* __restrict__ pks, int steps)
{
    __shared__ float Kls[2][16][68];
    __shared__ float Vls[2][16][68];

    const int nh = blockIdx.x;
    const int n = nh >> 4, h = nh & 15;
    const int chunk = blockIdx.y;
    const int l = threadIdx.x;
    const int half = l >> 5, col = l & 31;
    const int rb = l >> 4;          // staging row group 0..3 (rows 4rb..4rb+3)
    const int c4 = (l & 15) * 4;    // staging col

    const int s0 = chunk * steps * 16;
    const float* kb = keys   + ((size_t)(n * 4096 + s0) * 16 + h) * 64;
    const float* vb = values + ((size_t)(n * 4096 + s0) * 16 + h) * 64;
    const float* mb = mask + n * 4096 + s0;

    f32x16 acc[2][2];
    #pragma unroll
    for (int a = 0; a < 2; ++a)
        #pragma unroll
        for (int b = 0; b < 2; ++b)
            #pragma unroll
            for (int r = 0; r < 16; ++r) acc[a][b][r] = 0.f;

    float4 ks4 = make_float4(0.f, 0.f, 0.f, 0.f);

    float4 kA[4], vA[4], mA;
    float4 kB[4], vB[4], mB;

#define LOADSTEP(st, kd, vd, md)                                          \
    {                                                                     \
        _Pragma("unroll")                                                 \
        for (int jl = 0; jl < 4; ++jl) {                                  \
            const size_t off = (size_t)((st) * 16 + 4 * rb + jl) * 1024 + c4; \
            kd[jl] = *(const float4*)(kb + off);                          \
            vd[jl] = *(const float4*)(vb + off);                          \
        }                                                                 \
        md = *(const float4*)(mb + (st) * 16 + 4 * rb);                   \
    }

#define TRANSWRITE(kd, vd, md, p)                                         \
    {                                                                     \
        const float mm[4] = {md.x, md.y, md.z, md.w};                     \
        _Pragma("unroll")                                                 \
        for (int jl = 0; jl < 4; ++jl) {                                  \
            float4 kk = kd[jl];                                           \
            const float msk = mm[jl];                                     \
            kk.x = elu1(kk.x) * msk; kk.y = elu1(kk.y) * msk;             \
            kk.z = elu1(kk.z) * msk; kk.w = elu1(kk.w) * msk;             \
            ks4.x += kk.x; ks4.y += kk.y; ks4.z += kk.z; ks4.w += kk.w;   \
            *(float4*)&Kls[p][4 * rb + jl][c4] = kk;                      \
            *(float4*)&Vls[p][4 * rb + jl][c4] = vd[jl];                  \
        }                                                                 \
    }

#define FRAGMFMA(p)                                                       \
    {                                                                     \
        short8 ka0, ka1, va0, va1;                                        \
        _Pragma("unroll")                                                 \
        for (int jj = 0; jj < 8; ++jj) {                                  \
            const int s = 8 * half + jj;                                  \
            ka0[jj] = f2bf(Kls[p][s][col]);                               \
            ka1[jj] = f2bf(Kls[p][s][col + 32]);                          \
            va0[jj] = f2bf(Vls[p][s][col]);                               \
            va1[jj] = f2bf(Vls[p][s][col + 32]);                          \
        }                                                                 \
        acc[0][0] = __builtin_amdgcn_mfma_f32_32x32x16_bf16(ka0, va0, acc[0][0], 0, 0, 0); \
        acc[0][1] = __builtin_amdgcn_mfma_f32_32x32x16_bf16(ka0, va1, acc[0][1], 0, 0, 0); \
        acc[1][0] = __builtin_amdgcn_mfma_f32_32x32x16_bf16(ka1, va0, acc[1][0], 0, 0, 0); \
        acc[1][1] = __builtin_amdgcn_mfma_f32_32x32x16_bf16(ka1, va1, acc[1][1], 0, 0, 0); \
    }

    LOADSTEP(0, kA, vA, mA);
    TRANSWRITE(kA, vA, mA, 0);
    LOADSTEP(1, kB, vB, mB);

    for (int st = 0; st < steps; st += 2) {       // steps even (>=8)
        FRAGMFMA(0);                              // step st
        if (st + 2 < steps) LOADSTEP(st + 2, kA, vA, mA);
        TRANSWRITE(kB, vB, mB, 1);                // step st+1
        FRAGMFMA(1);                              // step st+1
        if (st + 3 < steps) LOADSTEP(st + 3, kB, vB, mB);
        if (st + 2 < steps) TRANSWRITE(kA, vA, mA, 0);   // step st+2
    }
#undef LOADSTEP
#undef TRANSWRITE
#undef FRAGMFMA

    // ksum partial: lane covers cols c4..c4+3 over its 4 row-groups; reduce
    // across rb groups (l^16, l^32) -> lanes 0..15 hold full column sums
    ks4.x += __shfl_xor(ks4.x, 16); ks4.y += __shfl_xor(ks4.y, 16);
    ks4.z += __shfl_xor(ks4.z, 16); ks4.w += __shfl_xor(ks4.w, 16);
    ks4.x += __shfl_xor(ks4.x, 32); ks4.y += __shfl_xor(ks4.y, 32);
    ks4.z += __shfl_xor(ks4.z, 32); ks4.w += __shfl_xor(ks4.w, 32);
    if (l < 16)
        *(float4*)(pks + ((size_t)chunk * 64 + nh) * 64 + l * 4) = ks4;

    // dump partial, already in [d][m] order; each store = 2x128B segments
    float* pb = pkv + ((size_t)chunk * 64 + nh) * 4096;
    #pragma unroll
    for (int td = 0; td < 2; ++td)
        #pragma unroll
        for (int tm = 0; tm < 2; ++tm)
            #pragma unroll
            for (int r = 0; r < 16; ++r) {
                const int d = 32 * td + (r & 3) + 8 * (r >> 2) + 4 * half;
                pb[(size_t)d * 64 + 32 * tm + col] = acc[td][tm][r];
            }
}

// ---------------------------------------------------------------------------
// Reduce: kvt[nh][d][m] = sum_c pkv[c][nh][d][m];  ksum[nh][d] = sum_c pks.
// ---------------------------------------------------------------------------
__global__ __launch_bounds__(256) void kv_reduce_kernel(
    const float* __restrict__ pkv, const float* __restrict__ pks,
    float* __restrict__ kvt, float* __restrict__ ksum, int CH)
{
    const int nh = blockIdx.x;
    const int f4 = blockIdx.y * 256 + threadIdx.x;   // float4 slot 0..1023
    float4 s4 = make_float4(0.f, 0.f, 0.f, 0.f);
    for (int c = 0; c < CH; ++c) {
        const float4 v = *(const float4*)(pkv + ((size_t)c * 64 + nh) * 4096 + f4 * 4);
        s4.x += v.x; s4.y += v.y; s4.z += v.z; s4.w += v.w;
    }
    *(float4*)(kvt + (size_t)nh * 4096 + f4 * 4) = s4;

    if (blockIdx.y == 0 && threadIdx.x < 64) {
        float s = 0.f;
        for (int c = 0; c < CH; ++c)
            s += pks[((size_t)c * 64 + nh) * 64 + threadIdx.x];
        ksum[nh * 64 + threadIdx.x] = s;
    }
}

// ---------------------------------------------------------------------------
// Phase 2: out[n,l,h,m] = z_l * sum_d Q'[l,d] * KVT[d,m],
//          z_l = 1/(sum_d Q'[l,d]*Ksum[d] + EPS)
// Round-7 rewrite: NO Q transpose (Qs row-major [l][d], pad 68 -> all LDS
// access conflict-free), 128 threads, thread tile 8l(strided by 16) x 8m
// (split 4+4 at m and m+32 -> fully coalesced 128B stores), z folded into
// the main loop (removes the serial Zs pass and the conflicted QsT writes
// that cost 3.67M conflict cycles in R6).
// ---------------------------------------------------------------------------
__global__ __launch_bounds__(128, 3) void out_kernel(
    const float* __restrict__ queries, const float* __restrict__ kvt,
    const float* __restrict__ ksum, float* __restrict__ out)
{
    __shared__ float Qs[128][68];   // [l][d]
    __shared__ float KVs[64][68];   // [d][m]
    __shared__ float Ksm[64];

    const int nh = blockIdx.x;
    const int n = nh >> 4, h = nh & 15;
    const int t = threadIdx.x;
    const int l0 = blockIdx.y * 128;

    // stage KVT: 1024 float4, 8 per thread
    #pragma unroll
    for (int k = 0; k < 8; ++k) {
        const int idx = t + k * 128;
        *(float4*)&KVs[idx >> 4][(idx & 15) * 4] =
            *(const float4*)(kvt + (size_t)nh * 4096 + idx * 4);
    }
    if (t < 64) Ksm[t] = ksum[nh * 64 + t];

    // stage Q' row-major: 2048 float4, 16 per thread (conflict-free writes)
    #pragma unroll
    for (int k = 0; k < 16; ++k) {
        const int idx = t + k * 128;
        const int row = idx >> 4, seg = idx & 15;
        const size_t g = ((size_t)(n * 4096 + l0 + row) * 16 + h) * 64 + seg * 4;
        float4 q4 = *(const float4*)(queries + g);
        q4.x = elu1(q4.x);
        q4.y = elu1(q4.y);
        q4.z = elu1(q4.z);
        q4.w = elu1(q4.w);
        *(float4*)&Qs[row][seg * 4] = q4;
    }
    __syncthreads();

    const int mg = t & 7;          // m-tile: 4mg..4mg+3 and 32+4mg..+3
    const int lg = t >> 3;         // 0..15; rows lg + 16*i

    float acc[8][8];
    float zacc[8];
    #pragma unroll
    for (int i = 0; i < 8; ++i) {
        zacc[i] = 0.f;
        #pragma unroll
        for (int j = 0; j < 8; ++j) acc[i][j] = 0.f;
    }

    float4 q[8];
    for (int d0 = 0; d0 < 64; d0 += 4) {
        const float4 km4 = *(const float4*)&Ksm[d0];
        #pragma unroll
        for (int i = 0; i < 8; ++i) {
            q[i] = *(const float4*)&Qs[lg + 16 * i][d0];
            zacc[i] += q[i].x * km4.x + q[i].y * km4.y +
                       q[i].z * km4.z + q[i].w * km4.w;
        }
        #pragma unroll
        for (int r = 0; r < 4; ++r) {
            const float4 kva = *(const float4*)&KVs[d0 + r][mg * 4];
            const float4 kvb = *(const float4*)&KVs[d0 + r][32 + mg * 4];
            #pragma unroll
            for (int i = 0; i < 8; ++i) {
                const float qc = ((const float*)&q[i])[r];
                acc[i][0] = fmaf(qc, kva.x, acc[i][0]);
                acc[i][1] = fmaf(qc, kva.y, acc[i][1]);
                acc[i][2] = fmaf(qc, kva.z, acc[i][2]);
                acc[i][3] = fmaf(qc, kva.w, acc[i][3]);
                acc[i][4] = fmaf(qc, kvb.x, acc[i][4]);
                acc[i][5] = fmaf(qc, kvb.y, acc[i][5]);
                acc[i][6] = fmaf(qc, kvb.z, acc[i][6]);
                acc[i][7] = fmaf(qc, kvb.w, acc[i][7]);
            }
        }
    }

    #pragma unroll
    for (int i = 0; i < 8; ++i) {
        const float z = 1.f / (zacc[i] + EPS);
        const int row = l0 + lg + 16 * i;
        const size_t g = ((size_t)(n * 4096 + row) * 16 + h) * 64;
        float4 o;
        o.x = acc[i][0] * z; o.y = acc[i][1] * z;
        o.z = acc[i][2] * z; o.w = acc[i][3] * z;
        *(float4*)(out + g + mg * 4) = o;
        o.x = acc[i][4] * z; o.y = acc[i][5] * z;
        o.z = acc[i][6] * z; o.w = acc[i][7] * z;
        *(float4*)(out + g + 32 + mg * 4) = o;
    }
}

extern "C" void kernel_launch(void* const* d_in, const int* in_sizes, int n_in,
                              void* d_out, int out_size, void* d_ws, size_t ws_size,
                              hipStream_t stream) {
    const float* queries = (const float*)d_in[0];
    const float* keys    = (const float*)d_in[1];
    const float* values  = (const float*)d_in[2];
    const float* mask    = (const float*)d_in[3];
    float* out = (float*)d_out;

    // one wave per (nh, chunk); adaptive chunk count vs workspace size
    int CH = 32;
    while (CH > 2) {
        size_t need = ((size_t)CH * 64 * 4096 + (size_t)CH * 64 * 64 +
                       (size_t)64 * 4096 + 64 * 64) * sizeof(float);
        if (need <= ws_size) break;
        CH >>= 1;
    }
    const int steps = 4096 / (CH * 16);   // 16-row K-steps per wave (even)

    float* pkv  = (float*)d_ws;                         // [CH][64][64][64] (d,m)
    float* pks  = pkv + (size_t)CH * 64 * 4096;         // [CH][64][64]
    float* kvt  = pks + (size_t)CH * 64 * 64;           // [64][64][64] (d,m)
    float* ksum = kvt + (size_t)64 * 4096;              // [64][64]

    kv_partial_kernel<<<dim3(64, CH), 64, 0, stream>>>(keys, values, mask,
                                                       pkv, pks, steps);
    kv_reduce_kernel<<<dim3(64, 4), 256, 0, stream>>>(pkv, pks, kvt, ksum, CH);
    out_kernel<<<dim3(64, 32), 128, 0, stream>>>(queries, kvt, ksum, out);
}

// Round 8
// 102.520 us; speedup vs baseline: 1.2324x; 1.2324x over previous
//
#include <hip/hip_runtime.h>

#define EPS 1e-6f

typedef __attribute__((ext_vector_type(8))) short short8;   // 8 x bf16 bits
typedef __attribute__((ext_vector_type(16))) float f32x16;  // MFMA 32x32 acc

__device__ __forceinline__ float elu1(float x) {
    // elu(x) + 1  ==  x > 0 ? x + 1 : exp(x)
    return x > 0.f ? x + 1.f : __expf(x);
}

// fp32 -> bf16 bits, round-to-nearest-even
__device__ __forceinline__ short f2bf(float x) {
    unsigned u = __float_as_uint(x);
    return (short)((u + 0x7FFFu + ((u >> 16) & 1u)) >> 16);
}

// ---------------------------------------------------------------------------
// Phase 1: KV partials via MFMA — R6 core (proven zero-spill: WRITE==pkv),
// repackaged for occupancy: CH=64 chunks, TWO independent waves per 128-thr
// block (no barriers, no LDS), grid (64, CH/2) -> 4096 waves (R6: 2048).
// Per-wave regs ~104 arch + 64 acc -> ~3 waves/SIMD; occupancy ~2.2x R6.
// Fragment mapping (verified R5-R7):
//   A (K'^T): lane holds d=l&31 (+32*td), k-elems s=8*(l>>5)+j
//   B (V):    lane holds m=l&31 (+32*tm), same k
//   C/D:      col=l&31, row=(r&3)+8*(r>>2)+4*(l>>5)
// ---------------------------------------------------------------------------
__global__ __launch_bounds__(128, 2) void kv_partial_kernel(
    const float* __restrict__ keys, const float* __restrict__ values,
    const float* __restrict__ mask, float* __restrict__ pkv,
    float* __restrict__ pks, int steps)
{
    const int nh = blockIdx.x;
    const int n = nh >> 4, h = nh & 15;
    const int t = threadIdx.x;
    const int w = t >> 6, l = t & 63;
    const int chunk = blockIdx.y * 2 + w;
    const int half = l >> 5, col = l & 31;

    const int s0 = chunk * steps * 16;
    const size_t rowbase = ((size_t)(n * 4096 + s0 + 8 * half) * 16 + h) * 64 + col;
    const float* kb = keys + rowbase;
    const float* vb = values + rowbase;
    const float* mb = mask + n * 4096 + s0 + 8 * half;

    f32x16 acc[2][2];
    #pragma unroll
    for (int a = 0; a < 2; ++a)
        #pragma unroll
        for (int b = 0; b < 2; ++b)
            #pragma unroll
            for (int r = 0; r < 16; ++r) acc[a][b][r] = 0.f;

    float ks0 = 0.f, ks1 = 0.f;

    float kA[16], vA[16], mA[8];
    float kB[16], vB[16], mB[8];

#define LOADSTEP(st, kd, vd, md)                                         \
    {                                                                    \
        const float* kp = kb + (size_t)(st) * 16384;                     \
        const float* vp = vb + (size_t)(st) * 16384;                     \
        const float* mp = mb + (st) * 16;                                \
        _Pragma("unroll")                                                \
        for (int j = 0; j < 8; ++j) {                                    \
            kd[2 * j]     = kp[(size_t)j * 1024];                        \
            kd[2 * j + 1] = kp[(size_t)j * 1024 + 32];                   \
            vd[2 * j]     = vp[(size_t)j * 1024];                        \
            vd[2 * j + 1] = vp[(size_t)j * 1024 + 32];                   \
            md[j]         = mp[j];                                       \
        }                                                                \
    }

#define COMPUTESTEP(kd, vd, md)                                          \
    {                                                                    \
        short8 ka0, ka1, va0, va1;                                       \
        _Pragma("unroll")                                                \
        for (int j = 0; j < 8; ++j) {                                    \
            const float msk = md[j];                                     \
            const float k0 = elu1(kd[2 * j]) * msk;                      \
            const float k1 = elu1(kd[2 * j + 1]) * msk;                  \
            ks0 += k0; ks1 += k1;                                        \
            ka0[j] = f2bf(k0); ka1[j] = f2bf(k1);                        \
            va0[j] = f2bf(vd[2 * j]); va1[j] = f2bf(vd[2 * j + 1]);      \
        }                                                                \
        acc[0][0] = __builtin_amdgcn_mfma_f32_32x32x16_bf16(ka0, va0, acc[0][0], 0, 0, 0); \
        acc[0][1] = __builtin_amdgcn_mfma_f32_32x32x16_bf16(ka0, va1, acc[0][1], 0, 0, 0); \
        acc[1][0] = __builtin_amdgcn_mfma_f32_32x32x16_bf16(ka1, va0, acc[1][0], 0, 0, 0); \
        acc[1][1] = __builtin_amdgcn_mfma_f32_32x32x16_bf16(ka1, va1, acc[1][1], 0, 0, 0); \
    }

    LOADSTEP(0, kA, vA, mA);
    for (int st = 0; st < steps; st += 2) {       // steps is even
        if (st + 1 < steps) LOADSTEP(st + 1, kB, vB, mB);
        COMPUTESTEP(kA, vA, mA);
        if (st + 2 < steps) LOADSTEP(st + 2, kA, vA, mA);
        if (st + 1 < steps) COMPUTESTEP(kB, vB, mB);
    }
#undef LOADSTEP
#undef COMPUTESTEP

    // ksum partial: ks0 covers d=col (this half's rows), ks1 covers d=col+32
    ks0 += __shfl_xor(ks0, 32);
    ks1 += __shfl_xor(ks1, 32);
    pks[((size_t)chunk * 64 + nh) * 64 + l] = half ? ks1 : ks0;

    // dump partial, already in [d][m] order; each store = 2x128B segments
    float* pb = pkv + ((size_t)chunk * 64 + nh) * 4096;
    #pragma unroll
    for (int td = 0; td < 2; ++td)
        #pragma unroll
        for (int tm = 0; tm < 2; ++tm)
            #pragma unroll
            for (int r = 0; r < 16; ++r) {
                const int d = 32 * td + (r & 3) + 8 * (r >> 2) + 4 * half;
                pb[(size_t)d * 64 + 32 * tm + col] = acc[td][tm][r];
            }
}

// ---------------------------------------------------------------------------
// Reduce: kvt[nh][d][m] = sum_c pkv[c][nh][d][m];  ksum[nh][d] = sum_c pks.
// unroll-4 keeps multiple loads in flight (runtime-CH loop was serialized).
// ---------------------------------------------------------------------------
__global__ __launch_bounds__(256) void kv_reduce_kernel(
    const float* __restrict__ pkv, const float* __restrict__ pks,
    float* __restrict__ kvt, float* __restrict__ ksum, int CH)
{
    const int nh = blockIdx.x;
    const int f4 = blockIdx.y * 256 + threadIdx.x;   // float4 slot 0..1023
    float4 s4 = make_float4(0.f, 0.f, 0.f, 0.f);
    #pragma unroll 4
    for (int c = 0; c < CH; ++c) {
        const float4 v = *(const float4*)(pkv + ((size_t)c * 64 + nh) * 4096 + f4 * 4);
        s4.x += v.x; s4.y += v.y; s4.z += v.z; s4.w += v.w;
    }
    *(float4*)(kvt + (size_t)nh * 4096 + f4 * 4) = s4;

    if (blockIdx.y == 0 && threadIdx.x < 64) {
        float s = 0.f;
        #pragma unroll 4
        for (int c = 0; c < CH; ++c)
            s += pks[((size_t)c * 64 + nh) * 64 + threadIdx.x];
        ksum[nh * 64 + threadIdx.x] = s;
    }
}

// ---------------------------------------------------------------------------
// Phase 2: out[n,l,h,m] = z_l * sum_d Q'[l,d] * KVT[d,m],
//          z_l = 1/(sum_d Q'[l,d]*Ksum[d] + EPS)
// R8: 64-row tiles -> LDS 35 KB -> 4 blocks/CU, 16 waves/CU (R7: 52.7 KB,
// 12.6% occupancy). 256 thr, tile 2l(stride 32) x 8m(split 4+4 at m,m+32).
// All LDS reads are broadcast or full-bank-spread (conflict-free); z folded
// into the d-loop. Small acc (16) -> low VGPR.
// ---------------------------------------------------------------------------
__global__ __launch_bounds__(256) void out_kernel(
    const float* __restrict__ queries, const float* __restrict__ kvt,
    const float* __restrict__ ksum, float* __restrict__ out)
{
    __shared__ float Qs[64][68];    // [l][d]
    __shared__ float KVs[64][68];   // [d][m]
    __shared__ float Ksm[64];

    const int nh = blockIdx.x;
    const int n = nh >> 4, h = nh & 15;
    const int t = threadIdx.x;
    const int l0 = blockIdx.y * 64;

    // stage KVT: 1024 float4, 4 per thread
    #pragma unroll
    for (int k = 0; k < 4; ++k) {
        const int idx = t + k * 256;
        *(float4*)&KVs[idx >> 4][(idx & 15) * 4] =
            *(const float4*)(kvt + (size_t)nh * 4096 + idx * 4);
    }
    if (t < 64) Ksm[t] = ksum[nh * 64 + t];

    // stage Q' row-major (+elu): 1024 float4, 4 per thread
    #pragma unroll
    for (int k = 0; k < 4; ++k) {
        const int idx = t + k * 256;
        const int row = idx >> 4, seg = idx & 15;
        const size_t g = ((size_t)(n * 4096 + l0 + row) * 16 + h) * 64 + seg * 4;
        float4 q4 = *(const float4*)(queries + g);
        q4.x = elu1(q4.x);
        q4.y = elu1(q4.y);
        q4.z = elu1(q4.z);
        q4.w = elu1(q4.w);
        *(float4*)&Qs[row][seg * 4] = q4;
    }
    __syncthreads();

    const int mg = t & 7;          // m cols 4mg..+3 and 32+4mg..+3
    const int lg = t >> 3;         // 0..31; rows lg, lg+32

    float acc[2][8];
    float zacc[2] = {0.f, 0.f};
    #pragma unroll
    for (int i = 0; i < 2; ++i)
        #pragma unroll
        for (int j = 0; j < 8; ++j) acc[i][j] = 0.f;

    #pragma unroll 4
    for (int d0 = 0; d0 < 64; d0 += 4) {
        const float4 km4 = *(const float4*)&Ksm[d0];
        float4 q[2];
        q[0] = *(const float4*)&Qs[lg][d0];
        q[1] = *(const float4*)&Qs[lg + 32][d0];
        #pragma unroll
        for (int i = 0; i < 2; ++i)
            zacc[i] += q[i].x * km4.x + q[i].y * km4.y +
                       q[i].z * km4.z + q[i].w * km4.w;
        #pragma unroll
        for (int r = 0; r < 4; ++r) {
            const float4 kva = *(const float4*)&KVs[d0 + r][mg * 4];
            const float4 kvb = *(const float4*)&KVs[d0 + r][32 + mg * 4];
            #pragma unroll
            for (int i = 0; i < 2; ++i) {
                const float qc = ((const float*)&q[i])[r];
                acc[i][0] = fmaf(qc, kva.x, acc[i][0]);
                acc[i][1] = fmaf(qc, kva.y, acc[i][1]);
                acc[i][2] = fmaf(qc, kva.z, acc[i][2]);
                acc[i][3] = fmaf(qc, kva.w, acc[i][3]);
                acc[i][4] = fmaf(qc, kvb.x, acc[i][4]);
                acc[i][5] = fmaf(qc, kvb.y, acc[i][5]);
                acc[i][6] = fmaf(qc, kvb.z, acc[i][6]);
                acc[i][7] = fmaf(qc, kvb.w, acc[i][7]);
            }
        }
    }

    #pragma unroll
    for (int i = 0; i < 2; ++i) {
        const float z = 1.f / (zacc[i] + EPS);
        const int row = l0 + lg + 32 * i;
        const size_t g = ((size_t)(n * 4096 + row) * 16 + h) * 64;
        float4 o;
        o.x = acc[i][0] * z; o.y = acc[i][1] * z;
        o.z = acc[i][2] * z; o.w = acc[i][3] * z;
        *(float4*)(out + g + mg * 4) = o;
        o.x = acc[i][4] * z; o.y = acc[i][5] * z;
        o.z = acc[i][6] * z; o.w = acc[i][7] * z;
        *(float4*)(out + g + 32 + mg * 4) = o;
    }
}

extern "C" void kernel_launch(void* const* d_in, const int* in_sizes, int n_in,
                              void* d_out, int out_size, void* d_ws, size_t ws_size,
                              hipStream_t stream) {
    const float* queries = (const float*)d_in[0];
    const float* keys    = (const float*)d_in[1];
    const float* values  = (const float*)d_in[2];
    const float* mask    = (const float*)d_in[3];
    float* out = (float*)d_out;

    // one wave per (nh, chunk); adaptive chunk count vs workspace size
    int CH = 64;
    while (CH > 2) {
        size_t need = ((size_t)CH * 64 * 4096 + (size_t)CH * 64 * 64 +
                       (size_t)64 * 4096 + 64 * 64) * sizeof(float);
        if (need <= ws_size) break;
        CH >>= 1;
    }
    const int steps = 4096 / (CH * 16);   // 16-row K-steps per wave (even)

    float* pkv  = (float*)d_ws;                         // [CH][64][64][64] (d,m)
    float* pks  = pkv + (size_t)CH * 64 * 4096;         // [CH][64][64]
    float* kvt  = pks + (size_t)CH * 64 * 64;           // [64][64][64] (d,m)
    float* ksum = kvt + (size_t)64 * 4096;              // [64][64]

    kv_partial_kernel<<<dim3(64, CH / 2), 128, 0, stream>>>(keys, values, mask,
                                                            pkv, pks, steps);
    kv_reduce_kernel<<<dim3(64, 4), 256, 0, stream>>>(pkv, pks, kvt, ksum, CH);
    out_kernel<<<dim3(64, 64), 256, 0, stream>>>(queries, kvt, ksum, out);
}

// Round 9
// 88.726 us; speedup vs baseline: 1.4241x; 1.1555x over previous
//
#include <hip/hip_runtime.h>

#define EPS 1e-6f

typedef __attribute__((ext_vector_type(8))) short short8;   // 8 x bf16 bits
typedef __attribute__((ext_vector_type(16))) float f32x16;  // MFMA 32x32 acc

__device__ __forceinline__ float elu1(float x) {
    // elu(x) + 1  ==  x > 0 ? x + 1 : exp(x)
    return x > 0.f ? x + 1.f : __expf(x);
}

// fp32 -> bf16 bits, round-to-nearest-even
__device__ __forceinline__ short f2bf(float x) {
    unsigned u = __float_as_uint(x);
    return (short)((u + 0x7FFFu + ((u >> 16) & 1u)) >> 16);
}

// async global->LDS, 16B per lane (global_load_lds_dwordx4).
// LDS dest = uniform base + lane*16; global src is per-lane.
__device__ __forceinline__ void gl16(const float* g, float* l) {
    __builtin_amdgcn_global_load_lds(
        (const __attribute__((address_space(1))) unsigned int*)g,
        (__attribute__((address_space(3))) unsigned int*)l, 16, 0, 0);
}

#define VMCNT(n) asm volatile("s_waitcnt vmcnt(" #n ")" ::: "memory")
#define LGKMCNT0() asm volatile("s_waitcnt lgkmcnt(0)" ::: "memory")

// ---------------------------------------------------------------------------
// Phase 1: KV partials via MFMA. One WAVE per (nh, chunk), wave-private LDS,
// no barriers, acc in AGPRs. R9 change: R5/R6/R8 were pinned at ~66 us by a
// per-CU VMEM-instruction bound (34 scalar loads/step; dur invariant across
// waves/prefetch/L3). Staging now uses global_load_lds width-16: 8 wide
// VMEM/step (K 4 + V 4) + 2 mask float4, double-buffered LDS [2][16][64]
// (linear as required; frag reads are 2-way bank = free), counted
// s_waitcnt vmcnt(10) — never 0 mid-loop. elu+mask+f2bf applied after the
// LDS read. Fragment mapping (verified R5-R8):
//   A (K'^T): lane holds d=l&31 (+32*td), k-elems s=8*(l>>5)+j
//   B (V):    lane holds m=l&31 (+32*tm), same k
//   C/D:      col=l&31, row=(r&3)+8*(r>>2)+4*(l>>5)
// ---------------------------------------------------------------------------
__global__ __launch_bounds__(64) void kv_partial_kernel(
    const float* __restrict__ keys, const float* __restrict__ values,
    const float* __restrict__ mask, float* __restrict__ pkv,
    float* __restrict__ pks, int steps)
{
    __shared__ float Kls[2][16][64];   // 8 KB
    __shared__ float Vls[2][16][64];   // 8 KB

    const int nh = blockIdx.x;
    const int n = nh >> 4, h = nh & 15;
    const int chunk = blockIdx.y;
    const int l = threadIdx.x;
    const int half = l >> 5, col = l & 31;

    const int s0 = chunk * steps * 16;
    const float* kb = keys   + ((size_t)(n * 4096 + s0) * 16 + h) * 64;
    const float* vb = values + ((size_t)(n * 4096 + s0) * 16 + h) * 64;
    const float* mb = mask + n * 4096 + s0 + 8 * half;

    // per-lane global offset within a 4-row group: row l>>4, col (l&15)*4
    const size_t lanerow = (size_t)(l >> 4) * 1024 + (size_t)(l & 15) * 4;

    f32x16 acc[2][2];
    #pragma unroll
    for (int a = 0; a < 2; ++a)
        #pragma unroll
        for (int b = 0; b < 2; ++b)
            #pragma unroll
            for (int r = 0; r < 16; ++r) acc[a][b][r] = 0.f;

    float ks0 = 0.f, ks1 = 0.f;
    float4 mA0, mA1, mB0, mB1;

#define ISSUE(st, p)                                                      \
    { _Pragma("unroll")                                                   \
      for (int q = 0; q < 4; ++q) {                                       \
          const size_t go = (size_t)((st) * 16 + 4 * q) * 1024 + lanerow; \
          gl16(kb + go, &Kls[p][4 * q][0]);                               \
          gl16(vb + go, &Vls[p][4 * q][0]);                               \
      } }

#define MASKLD(st, m0, m1)                                                \
    { m0 = *(const float4*)(mb + (st) * 16);                              \
      m1 = *(const float4*)(mb + (st) * 16 + 4); }

#define COMPUTE(p, m0, m1)                                                \
    { short8 ka0, ka1, va0, va1;                                          \
      const float mm[8] = {m0.x, m0.y, m0.z, m0.w, m1.x, m1.y, m1.z, m1.w}; \
      _Pragma("unroll")                                                   \
      for (int j = 0; j < 8; ++j) {                                       \
          const int s = 8 * half + j;                                     \
          const float k0 = elu1(Kls[p][s][col]) * mm[j];                  \
          const float k1 = elu1(Kls[p][s][col + 32]) * mm[j];             \
          ks0 += k0; ks1 += k1;                                           \
          ka0[j] = f2bf(k0); ka1[j] = f2bf(k1);                           \
          va0[j] = f2bf(Vls[p][s][col]);                                  \
          va1[j] = f2bf(Vls[p][s][col + 32]);                             \
      }                                                                   \
      LGKMCNT0();                                                         \
      acc[0][0] = __builtin_amdgcn_mfma_f32_32x32x16_bf16(ka0, va0, acc[0][0], 0, 0, 0); \
      acc[0][1] = __builtin_amdgcn_mfma_f32_32x32x16_bf16(ka0, va1, acc[0][1], 0, 0, 0); \
      acc[1][0] = __builtin_amdgcn_mfma_f32_32x32x16_bf16(ka1, va0, acc[1][0], 0, 0, 0); \
      acc[1][1] = __builtin_amdgcn_mfma_f32_32x32x16_bf16(ka1, va1, acc[1][1], 0, 0, 0); \
    }

    // prologue: two steps in flight, wait for step 0 (10 = step 1's ops)
    ISSUE(0, 0); MASKLD(0, mA0, mA1);
    ISSUE(1, 1); MASKLD(1, mB0, mB1);
    VMCNT(10);

    for (int st = 0; st < steps; st += 2) {       // steps even (>=8)
        COMPUTE(0, mA0, mA1);                     // step st
        if (st + 2 < steps) { ISSUE(st + 2, 0); MASKLD(st + 2, mA0, mA1); VMCNT(10); }
        else { VMCNT(0); }
        COMPUTE(1, mB0, mB1);                     // step st+1
        if (st + 3 < steps) { ISSUE(st + 3, 1); MASKLD(st + 3, mB0, mB1); VMCNT(10); }
        else { VMCNT(0); }
    }
#undef ISSUE
#undef MASKLD
#undef COMPUTE

    // ksum partial: ks0 covers d=col (this half's rows), ks1 covers d=col+32
    ks0 += __shfl_xor(ks0, 32);
    ks1 += __shfl_xor(ks1, 32);
    pks[((size_t)chunk * 64 + nh) * 64 + l] = half ? ks1 : ks0;

    // dump partial, already in [d][m] order; each store = 2x128B segments
    float* pb = pkv + ((size_t)chunk * 64 + nh) * 4096;
    #pragma unroll
    for (int td = 0; td < 2; ++td)
        #pragma unroll
        for (int tm = 0; tm < 2; ++tm)
            #pragma unroll
            for (int r = 0; r < 16; ++r) {
                const int d = 32 * td + (r & 3) + 8 * (r >> 2) + 4 * half;
                pb[(size_t)d * 64 + 32 * tm + col] = acc[td][tm][r];
            }
}

// ---------------------------------------------------------------------------
// Reduce: kvt[nh][d][m] = sum_c pkv[c][nh][d][m];  ksum[nh][d] = sum_c pks.
// ---------------------------------------------------------------------------
__global__ __launch_bounds__(256) void kv_reduce_kernel(
    const float* __restrict__ pkv, const float* __restrict__ pks,
    float* __restrict__ kvt, float* __restrict__ ksum, int CH)
{
    const int nh = blockIdx.x;
    const int f4 = blockIdx.y * 256 + threadIdx.x;   // float4 slot 0..1023
    float4 s4 = make_float4(0.f, 0.f, 0.f, 0.f);
    #pragma unroll 4
    for (int c = 0; c < CH; ++c) {
        const float4 v = *(const float4*)(pkv + ((size_t)c * 64 + nh) * 4096 + f4 * 4);
        s4.x += v.x; s4.y += v.y; s4.z += v.z; s4.w += v.w;
    }
    *(float4*)(kvt + (size_t)nh * 4096 + f4 * 4) = s4;

    if (blockIdx.y == 0 && threadIdx.x < 64) {
        float s = 0.f;
        #pragma unroll 4
        for (int c = 0; c < CH; ++c)
            s += pks[((size_t)c * 64 + nh) * 64 + threadIdx.x];
        ksum[nh * 64 + threadIdx.x] = s;
    }
}

// ---------------------------------------------------------------------------
// Phase 2: out[n,l,h,m] = z_l * sum_d Q'[l,d] * KVT[d,m],
//          z_l = 1/(sum_d Q'[l,d]*Ksum[d] + EPS)
// R8 version (kept): 64-row tiles, LDS 35 KB, 256 thr, 16 waves/CU,
// conflict-free LDS, z folded into the d-loop.
// ---------------------------------------------------------------------------
__global__ __launch_bounds__(256) void out_kernel(
    const float* __restrict__ queries, const float* __restrict__ kvt,
    const float* __restrict__ ksum, float* __restrict__ out)
{
    __shared__ float Qs[64][68];    // [l][d]
    __shared__ float KVs[64][68];   // [d][m]
    __shared__ float Ksm[64];

    const int nh = blockIdx.x;
    const int n = nh >> 4, h = nh & 15;
    const int t = threadIdx.x;
    const int l0 = blockIdx.y * 64;

    #pragma unroll
    for (int k = 0; k < 4; ++k) {
        const int idx = t + k * 256;
        *(float4*)&KVs[idx >> 4][(idx & 15) * 4] =
            *(const float4*)(kvt + (size_t)nh * 4096 + idx * 4);
    }
    if (t < 64) Ksm[t] = ksum[nh * 64 + t];

    #pragma unroll
    for (int k = 0; k < 4; ++k) {
        const int idx = t + k * 256;
        const int row = idx >> 4, seg = idx & 15;
        const size_t g = ((size_t)(n * 4096 + l0 + row) * 16 + h) * 64 + seg * 4;
        float4 q4 = *(const float4*)(queries + g);
        q4.x = elu1(q4.x);
        q4.y = elu1(q4.y);
        q4.z = elu1(q4.z);
        q4.w = elu1(q4.w);
        *(float4*)&Qs[row][seg * 4] = q4;
    }
    __syncthreads();

    const int mg = t & 7;          // m cols 4mg..+3 and 32+4mg..+3
    const int lg = t >> 3;         // 0..31; rows lg, lg+32

    float acc[2][8];
    float zacc[2] = {0.f, 0.f};
    #pragma unroll
    for (int i = 0; i < 2; ++i)
        #pragma unroll
        for (int j = 0; j < 8; ++j) acc[i][j] = 0.f;

    #pragma unroll 4
    for (int d0 = 0; d0 < 64; d0 += 4) {
        const float4 km4 = *(const float4*)&Ksm[d0];
        float4 q[2];
        q[0] = *(const float4*)&Qs[lg][d0];
        q[1] = *(const float4*)&Qs[lg + 32][d0];
        #pragma unroll
        for (int i = 0; i < 2; ++i)
            zacc[i] += q[i].x * km4.x + q[i].y * km4.y +
                       q[i].z * km4.z + q[i].w * km4.w;
        #pragma unroll
        for (int r = 0; r < 4; ++r) {
            const float4 kva = *(const float4*)&KVs[d0 + r][mg * 4];
            const float4 kvb = *(const float4*)&KVs[d0 + r][32 + mg * 4];
            #pragma unroll
            for (int i = 0; i < 2; ++i) {
                const float qc = ((const float*)&q[i])[r];
                acc[i][0] = fmaf(qc, kva.x, acc[i][0]);
                acc[i][1] = fmaf(qc, kva.y, acc[i][1]);
                acc[i][2] = fmaf(qc, kva.z, acc[i][2]);
                acc[i][3] = fmaf(qc, kva.w, acc[i][3]);
                acc[i][4] = fmaf(qc, kvb.x, acc[i][4]);
                acc[i][5] = fmaf(qc, kvb.y, acc[i][5]);
                acc[i][6] = fmaf(qc, kvb.z, acc[i][6]);
                acc[i][7] = fmaf(qc, kvb.w, acc[i][7]);
            }
        }
    }

    #pragma unroll
    for (int i = 0; i < 2; ++i) {
        const float z = 1.f / (zacc[i] + EPS);
        const int row = l0 + lg + 32 * i;
        const size_t g = ((size_t)(n * 4096 + row) * 16 + h) * 64;
        float4 o;
        o.x = acc[i][0] * z; o.y = acc[i][1] * z;
        o.z = acc[i][2] * z; o.w = acc[i][3] * z;
        *(float4*)(out + g + mg * 4) = o;
        o.x = acc[i][4] * z; o.y = acc[i][5] * z;
        o.z = acc[i][6] * z; o.w = acc[i][7] * z;
        *(float4*)(out + g + 32 + mg * 4) = o;
    }
}

extern "C" void kernel_launch(void* const* d_in, const int* in_sizes, int n_in,
                              void* d_out, int out_size, void* d_ws, size_t ws_size,
                              hipStream_t stream) {
    const float* queries = (const float*)d_in[0];
    const float* keys    = (const float*)d_in[1];
    const float* values  = (const float*)d_in[2];
    const float* mask    = (const float*)d_in[3];
    float* out = (float*)d_out;

    // one wave per (nh, chunk); adaptive chunk count vs workspace size
    int CH = 32;
    while (CH > 2) {
        size_t need = ((size_t)CH * 64 * 4096 + (size_t)CH * 64 * 64 +
                       (size_t)64 * 4096 + 64 * 64) * sizeof(float);
        if (need <= ws_size) break;
        CH >>= 1;
    }
    const int steps = 4096 / (CH * 16);   // 16-row K-steps per wave (even)

    float* pkv  = (float*)d_ws;                         // [CH][64][64][64] (d,m)
    float* pks  = pkv + (size_t)CH * 64 * 4096;         // [CH][64][64]
    float* kvt  = pks + (size_t)CH * 64 * 64;           // [64][64][64] (d,m)
    float* ksum = kvt + (size_t)64 * 4096;              // [64][64]

    kv_partial_kernel<<<dim3(64, CH), 64, 0, stream>>>(keys, values, mask,
                                                       pkv, pks, steps);
    kv_reduce_kernel<<<dim3(64, 4), 256, 0, stream>>>(pkv, pks, kvt, ksum, CH);
    out_kernel<<<dim3(64, 64), 256, 0, stream>>>(queries, kvt, ksum, out);
}